// Round 1
// baseline (1723.597 us; speedup 1.0000x reference)
//
#include <hip/hip_runtime.h>
#include <hip/hip_bf16.h>
#include <math.h>

#define N_USER 100000
#define N_ITEM 50000
#define NNODE  150000   // N_USER + N_ITEM
#define DIM    64
#define NEDGE  2000000
#define BSZ    8192

__device__ __forceinline__ float logsigf(float x){
    // log_sigmoid(x) = min(x,0) - log1p(exp(-|x|))
    return fminf(x, 0.f) - log1pf(expf(-fabsf(x)));
}
__device__ __forceinline__ float softplusf(float x){
    // softplus(x) = max(x,0) + log1p(exp(-|x|))
    return fmaxf(x, 0.f) + log1pf(expf(-fabsf(x)));
}

// ---- degree count: 2 int atomics per edge -------------------------------
__global__ void k_deg(const int* __restrict__ src, const int* __restrict__ dst,
                      unsigned* __restrict__ degO, unsigned* __restrict__ degI){
    int e = blockIdx.x*blockDim.x + threadIdx.x;
    if(e >= NEDGE) return;
    atomicAdd(&degO[src[e]], 1u);
    atomicAdd(&degI[dst[e]], 1u);
}

// ---- exclusive scan of deg_in -> rowstart (3-kernel classic) ------------
__global__ void k_scan1(const unsigned* __restrict__ deg, unsigned* __restrict__ rs,
                        unsigned* __restrict__ bsums){
    __shared__ unsigned sh[1024];
    int i = blockIdx.x*1024 + threadIdx.x;
    unsigned v = (i < NNODE) ? deg[i] : 0u;
    sh[threadIdx.x] = v;
    __syncthreads();
    for(int off=1; off<1024; off<<=1){
        unsigned t = (threadIdx.x >= off) ? sh[threadIdx.x-off] : 0u;
        __syncthreads();
        sh[threadIdx.x] += t;
        __syncthreads();
    }
    if(i < NNODE) rs[i] = sh[threadIdx.x] - v;   // exclusive
    if(threadIdx.x == 1023) bsums[blockIdx.x] = sh[1023];
}

__global__ void k_scan2(unsigned* bsums, int nb){
    if(threadIdx.x==0 && blockIdx.x==0){
        unsigned run=0;
        for(int i=0;i<nb;i++){ unsigned v=bsums[i]; bsums[i]=run; run+=v; }
    }
}

__global__ void k_scan3(unsigned* __restrict__ rs, const unsigned* __restrict__ bsums){
    int i = blockIdx.x*1024 + threadIdx.x;
    if(i < NNODE) rs[i] += bsums[blockIdx.x];
}

// ---- bucket edges into CSR-by-dst; fold sym-norm weight into val --------
__global__ void k_bucket(const int* __restrict__ src, const int* __restrict__ dst,
                         const unsigned* __restrict__ degO, const unsigned* __restrict__ degI,
                         const unsigned* __restrict__ rs, unsigned* __restrict__ cursor,
                         int* __restrict__ col, float* __restrict__ val){
    int e = blockIdx.x*blockDim.x + threadIdx.x;
    if(e >= NEDGE) return;
    int s = src[e], d = dst[e];
    float w = rsqrtf(fmaxf((float)degO[s],1.f)) * rsqrtf(fmaxf((float)degI[d],1.f));
    unsigned pos = rs[d] + atomicAdd(&cursor[d],1u);
    col[pos] = s; val[pos] = w;
}

// ---- SpMM as pure gather: one wave per dst row, lane = dim --------------
__global__ __launch_bounds__(256) void k_spmm(const float* __restrict__ hin, float* __restrict__ hout,
                       const unsigned* __restrict__ rs, const unsigned* __restrict__ degI,
                       const int* __restrict__ col, const float* __restrict__ val){
    int w = (blockIdx.x*blockDim.x + threadIdx.x) >> 6;
    int lane = threadIdx.x & 63;
    if(w >= NNODE) return;
    unsigned start = rs[w], cnt = degI[w];
    float acc = 0.f;
    for(unsigned i=0;i<cnt;i++){
        int s = col[start+i];
        float wv = val[start+i];
        acc += wv * hin[(size_t)s*DIM + lane];   // coalesced 256B row read
    }
    hout[(size_t)w*DIM + lane] = acc;
}

// ---- accumulate layer outputs at the 3B gathered rows only --------------
__global__ void k_gacc(const float* __restrict__ h, float* __restrict__ facc,
                       const int* __restrict__ user, const int* __restrict__ itp,
                       const int* __restrict__ itn, int init){
    int t = blockIdx.x*blockDim.x + threadIdx.x;
    int j = t >> 6, lane = t & 63;
    if(j >= 3*BSZ) return;
    int sec = j >> 13, b = j & (BSZ-1);       // BSZ = 2^13
    int node = (sec==0) ? user[b] : ((sec==1) ? itp[b]+N_USER : itn[b]+N_USER);
    float v = h[(size_t)node*DIM + lane];
    if(init) facc[t] = v; else facc[t] += v;
}

// ---- per-sample dot-product scores (facc holds 4*f, so /16) -------------
__global__ void k_score(const float* __restrict__ facc, float* __restrict__ pout, float* __restrict__ nout){
    int t = blockIdx.x*blockDim.x + threadIdx.x;
    int b = t >> 6, lane = t & 63;
    if(b >= BSZ) return;
    float u = facc[(size_t)b*DIM + lane];
    float dp = u * facc[(size_t)(BSZ   + b)*DIM + lane];
    float dn = u * facc[(size_t)(2*BSZ + b)*DIM + lane];
    for(int off=32; off; off>>=1){ dp += __shfl_down(dp,off,64); dn += __shfl_down(dn,off,64); }
    if(lane==0){ pout[b] = dp*(1.f/16.f); nout[b] = dn*(1.f/16.f); }
}

// ---- detect mask upload layout: 1-byte bool vs int32 --------------------
// If any byte at index i%4!=0 within the first BSZ bytes is nonzero, the
// buffer is a byte-per-element bool array. Otherwise it must be int32
// (prob. of false positive for random bools ~2^-6144). Never reads OOB.
__global__ void k_maskdetect(const unsigned char* __restrict__ m, unsigned* __restrict__ flag){
    __shared__ int any;
    if(threadIdx.x==0) any=0;
    __syncthreads();
    for(int i=threadIdx.x;i<BSZ;i+=blockDim.x){ if((i&3) && m[i]) any=1; }
    __syncthreads();
    if(threadIdx.x==0) *flag = (any!=0) ? 1u : 0u;   // 1 = byte layout
}

// ---- final fused loss, single block -------------------------------------
__global__ __launch_bounds__(256) void k_loss(const float* __restrict__ p_int, const float* __restrict__ n_int,
                      const float* __restrict__ p_pop, const float* __restrict__ n_pop,
                      const float* __restrict__ q, const float* __restrict__ bq,
                      const int* __restrict__ item_p, const int* __restrict__ item_n,
                      const void* __restrict__ mask, const unsigned* __restrict__ mflag,
                      float* __restrict__ out){
    __shared__ float sh[4][256];
    float a0=0,a1=0,a2=0,a3=0;
    bool bytes = (*mflag)!=0;
    const unsigned char* m8 = (const unsigned char*)mask;
    const int* m32 = (const int*)mask;
    for(int i=threadIdx.x;i<BSZ;i+=256){
        float pi=p_int[i], ni=n_int[i], pp=p_pop[i], npp=n_pop[i];
        float mf = bytes ? (m8[i]?1.f:0.f) : (m32[i]?1.f:0.f);
        float nmf = 1.f-mf;
        a0 += mf  * logsigf(pi-ni);        // loss_int numerator
        a1 += mf  * logsigf(npp-pp);       // mask_bpr(n_pop, p_pop, mf)
        a2 += nmf * logsigf(pp-npp);       // mask_bpr(p_pop, n_pop, nmf)
        int ip=item_p[i], in_=item_n[i];
        float popp = softplusf(q[ip]) + softplusf(bq[ip]);
        float popn = softplusf(q[in_]) + softplusf(bq[in_]);
        a3 += logsigf(tanhf(popp)*(pi+pp) - tanhf(popn)*(ni+npp));
    }
    sh[0][threadIdx.x]=a0; sh[1][threadIdx.x]=a1; sh[2][threadIdx.x]=a2; sh[3][threadIdx.x]=a3;
    __syncthreads();
    for(int off=128; off; off>>=1){
        if(threadIdx.x < off){
            sh[0][threadIdx.x]+=sh[0][threadIdx.x+off];
            sh[1][threadIdx.x]+=sh[1][threadIdx.x+off];
            sh[2][threadIdx.x]+=sh[2][threadIdx.x+off];
            sh[3][threadIdx.x]+=sh[3][threadIdx.x+off];
        }
        __syncthreads();
    }
    if(threadIdx.x==0){
        const float invB = 1.f/(float)BSZ;
        float loss_int  = -sh[0][0]*invB;
        float loss_pop  = -sh[1][0]*invB + sh[2][0]*invB;
        float loss_tide = -sh[3][0]*invB;
        out[0] = 0.1f*loss_int + 0.1f*loss_pop + 0.2f*loss_tide;
    }
}

extern "C" void kernel_launch(void* const* d_in, const int* in_sizes, int n_in,
                              void* d_out, int out_size, void* d_ws, size_t ws_size,
                              hipStream_t stream){
    const float* emb_int = (const float*)d_in[0];
    const float* emb_pop = (const float*)d_in[1];
    const float* q    = (const float*)d_in[2];
    const float* bq   = (const float*)d_in[3];
    const int* user   = (const int*)d_in[4];
    const int* item_p = (const int*)d_in[5];
    const int* item_n = (const int*)d_in[6];
    const void* mask  = d_in[7];
    const int* esrc   = (const int*)d_in[8];
    const int* edst   = (const int*)d_in[9];

    char* ws = (char*)d_ws;
    size_t o = 0;
    auto take = [&](size_t bytes)->char*{ char* p = ws + o; o = (o + bytes + 255) & ~(size_t)255; return p; };
    unsigned* degO   = (unsigned*)take((size_t)NNODE*4);
    unsigned* degI   = (unsigned*)take((size_t)NNODE*4);
    unsigned* cursor = (unsigned*)take((size_t)NNODE*4);
    size_t zeroBytes = o;                       // degO, degI, cursor need zeros
    unsigned* rs     = (unsigned*)take((size_t)NNODE*4);
    unsigned* bsums  = (unsigned*)take(1024*4);
    int*      col    = (int*)take((size_t)NEDGE*4);
    float*    val    = (float*)take((size_t)NEDGE*4);
    float*    hA     = (float*)take((size_t)NNODE*DIM*4);
    float*    hB     = (float*)take((size_t)NNODE*DIM*4);
    float*    facc   = (float*)take((size_t)3*BSZ*DIM*4);
    float*    sc     = (float*)take((size_t)4*BSZ*4);
    unsigned* mflag  = (unsigned*)take(256);
    (void)ws_size; (void)in_sizes; (void)n_in; (void)out_size;

    float* p_int = sc;          float* n_int = sc + BSZ;
    float* p_pop = sc + 2*BSZ;  float* n_pop = sc + 3*BSZ;

    hipMemsetAsync(ws, 0, zeroBytes, stream);

    const int eb = (NEDGE + 255)/256;
    k_deg<<<eb,256,0,stream>>>(esrc, edst, degO, degI);
    const int sb = (NNODE + 1023)/1024;
    k_scan1<<<sb,1024,0,stream>>>(degI, rs, bsums);
    k_scan2<<<1,64,0,stream>>>(bsums, sb);
    k_scan3<<<sb,1024,0,stream>>>(rs, bsums);
    k_bucket<<<eb,256,0,stream>>>(esrc, edst, degO, degI, rs, cursor, col, val);
    k_maskdetect<<<1,256,0,stream>>>((const unsigned char*)mask, mflag);

    const int gaccB = (3*BSZ*DIM + 255)/256;
    const int spB   = (NNODE*DIM + 255)/256;   // one wave (64 lanes) per row
    const int scB   = (BSZ*DIM + 255)/256;

    for(int ph=0; ph<2; ++ph){
        const float* e0 = ph ? emb_pop : emb_int;
        k_gacc<<<gaccB,256,0,stream>>>(e0, facc, user, item_p, item_n, 1);
        k_spmm<<<spB,256,0,stream>>>(e0, hA, rs, degI, col, val);
        k_gacc<<<gaccB,256,0,stream>>>(hA, facc, user, item_p, item_n, 0);
        k_spmm<<<spB,256,0,stream>>>(hA, hB, rs, degI, col, val);
        k_gacc<<<gaccB,256,0,stream>>>(hB, facc, user, item_p, item_n, 0);
        k_spmm<<<spB,256,0,stream>>>(hB, hA, rs, degI, col, val);
        k_gacc<<<gaccB,256,0,stream>>>(hA, facc, user, item_p, item_n, 0);
        float* pp = ph ? p_pop : p_int;
        float* nn = ph ? n_pop : n_int;
        k_score<<<scB,256,0,stream>>>(facc, pp, nn);
    }
    k_loss<<<1,256,0,stream>>>(p_int,n_int,p_pop,n_pop,q,bq,item_p,item_n,mask,mflag,(float*)d_out);
}

// Round 2
// 734.366 us; speedup vs baseline: 2.3471x; 2.3471x over previous
//
#include <hip/hip_runtime.h>
#include <hip/hip_bf16.h>
#include <hip/hip_fp16.h>
#include <math.h>

#define N_USER 100000
#define N_ITEM 50000
#define NNODE  150000   // N_USER + N_ITEM
#define DIM    64
#define NEDGE  2000000
#define BSZ    8192
#define NTGT   (3*BSZ)

__device__ __forceinline__ float logsigf(float x){
    return fminf(x, 0.f) - log1pf(expf(-fabsf(x)));
}
__device__ __forceinline__ float softplusf(float x){
    return fmaxf(x, 0.f) + log1pf(expf(-fabsf(x)));
}

// ---- degree count -------------------------------------------------------
__global__ void k_deg(const int* __restrict__ src, const int* __restrict__ dst,
                      unsigned* __restrict__ degO, unsigned* __restrict__ degI){
    int e = blockIdx.x*blockDim.x + threadIdx.x;
    if(e >= NEDGE) return;
    atomicAdd(&degO[src[e]], 1u);
    atomicAdd(&degI[dst[e]], 1u);
}

// ---- exclusive scan of deg_in -> rowstart -------------------------------
__global__ void k_scan1(const unsigned* __restrict__ deg, unsigned* __restrict__ rs,
                        unsigned* __restrict__ bsums){
    __shared__ unsigned sh[1024];
    int i = blockIdx.x*1024 + threadIdx.x;
    unsigned v = (i < NNODE) ? deg[i] : 0u;
    sh[threadIdx.x] = v;
    __syncthreads();
    for(int off=1; off<1024; off<<=1){
        unsigned t = (threadIdx.x >= off) ? sh[threadIdx.x-off] : 0u;
        __syncthreads();
        sh[threadIdx.x] += t;
        __syncthreads();
    }
    if(i < NNODE) rs[i] = sh[threadIdx.x] - v;
    if(threadIdx.x == 1023) bsums[blockIdx.x] = sh[1023];
}

__global__ void k_scan2(unsigned* bsums, int nb){
    if(threadIdx.x==0 && blockIdx.x==0){
        unsigned run=0;
        for(int i=0;i<nb;i++){ unsigned v=bsums[i]; bsums[i]=run; run+=v; }
    }
}

__global__ void k_scan3(unsigned* __restrict__ rs, const unsigned* __restrict__ bsums){
    int i = blockIdx.x*1024 + threadIdx.x;
    if(i < NNODE) rs[i] += bsums[blockIdx.x];
}

// ---- bucket edges into CSR-by-dst, packed (col, weight-bits) ------------
__global__ void k_bucket(const int* __restrict__ src, const int* __restrict__ dst,
                         const unsigned* __restrict__ degO, const unsigned* __restrict__ degI,
                         const unsigned* __restrict__ rs, unsigned* __restrict__ cursor,
                         int2* __restrict__ ec){
    int e = blockIdx.x*blockDim.x + threadIdx.x;
    if(e >= NEDGE) return;
    int s = src[e], d = dst[e];
    float w = rsqrtf(fmaxf((float)degO[s],1.f)) * rsqrtf(fmaxf((float)degI[d],1.f));
    unsigned pos = rs[d] + atomicAdd(&cursor[d],1u);
    ec[pos] = make_int2(s, __float_as_int(w));
}

// ---- interleave emb_int|emb_pop into fp16 combined rows [node][128] -----
__global__ void k_prep(const float2* __restrict__ ei, const float2* __restrict__ ep,
                       __half2* __restrict__ hC){
    int idx = blockIdx.x*blockDim.x + threadIdx.x;
    if(idx >= NNODE*32) return;
    int n = idx>>5, p = idx&31;
    hC[(size_t)n*64 + p]      = __float22half2_rn(ei[(size_t)n*32+p]);
    hC[(size_t)n*64 + 32 + p] = __float22half2_rn(ep[(size_t)n*32+p]);
}

// ---- combined SpMM (both tables at once), one wave per dst row ----------
__global__ __launch_bounds__(256) void k_spmm_c(const __half2* __restrict__ hin, __half2* __restrict__ hout,
                                                const unsigned* __restrict__ rs, const unsigned* __restrict__ degI,
                                                const int2* __restrict__ ec){
    int w = (blockIdx.x*blockDim.x + threadIdx.x) >> 6;
    int lane = threadIdx.x & 63;
    if(w >= NNODE) return;
    unsigned start = (unsigned)__builtin_amdgcn_readfirstlane((int)rs[w]);
    unsigned cnt   = (unsigned)__builtin_amdgcn_readfirstlane((int)degI[w]);
    float ax=0.f, ay=0.f;
    unsigned i=0;
    for(; i+2<=cnt; i+=2){
        int2 e0 = ec[start+i];
        int2 e1 = ec[start+i+1];
        float w0 = __int_as_float(e0.y), w1 = __int_as_float(e1.y);
        float2 v0 = __half22float2(hin[(size_t)e0.x*64 + lane]);
        float2 v1 = __half22float2(hin[(size_t)e1.x*64 + lane]);
        ax += w0*v0.x; ay += w0*v0.y;
        ax += w1*v1.x; ay += w1*v1.y;
    }
    if(i<cnt){
        int2 e0 = ec[start+i];
        float w0 = __int_as_float(e0.y);
        float2 v0 = __half22float2(hin[(size_t)e0.x*64 + lane]);
        ax += w0*v0.x; ay += w0*v0.y;
    }
    hout[(size_t)w*64 + lane] = __float22half2_rn(make_float2(ax,ay));
}

// ---- layer-3 SpMM restricted to target rows, accumulate fp32 ------------
__global__ __launch_bounds__(256) void k_spmm_t(const __half2* __restrict__ hin, float2* __restrict__ faccv,
                                                const unsigned* __restrict__ rs, const unsigned* __restrict__ degI,
                                                const int2* __restrict__ ec, const int* __restrict__ tlist){
    int w = (blockIdx.x*blockDim.x + threadIdx.x) >> 6;
    int lane = threadIdx.x & 63;
    if(w >= NTGT) return;
    int node = __builtin_amdgcn_readfirstlane(tlist[w]);
    unsigned start = (unsigned)__builtin_amdgcn_readfirstlane((int)rs[node]);
    unsigned cnt   = (unsigned)__builtin_amdgcn_readfirstlane((int)degI[node]);
    float ax=0.f, ay=0.f;
    unsigned i=0;
    for(; i+2<=cnt; i+=2){
        int2 e0 = ec[start+i];
        int2 e1 = ec[start+i+1];
        float w0 = __int_as_float(e0.y), w1 = __int_as_float(e1.y);
        float2 v0 = __half22float2(hin[(size_t)e0.x*64 + lane]);
        float2 v1 = __half22float2(hin[(size_t)e1.x*64 + lane]);
        ax += w0*v0.x; ay += w0*v0.y;
        ax += w1*v1.x; ay += w1*v1.y;
    }
    if(i<cnt){
        int2 e0 = ec[start+i];
        float w0 = __int_as_float(e0.y);
        float2 v0 = __half22float2(hin[(size_t)e0.x*64 + lane]);
        ax += w0*v0.x; ay += w0*v0.y;
    }
    float2 a = faccv[(size_t)w*64 + lane];
    a.x += ax; a.y += ay;
    faccv[(size_t)w*64 + lane] = a;
}

// ---- target node-id list ------------------------------------------------
__global__ void k_tlist(const int* __restrict__ user, const int* __restrict__ itp,
                        const int* __restrict__ itn, int* __restrict__ tlist){
    int j = blockIdx.x*blockDim.x + threadIdx.x;
    if(j >= NTGT) return;
    int sec = j>>13, b = j&(BSZ-1);
    tlist[j] = (sec==0) ? user[b] : ((sec==1) ? itp[b]+N_USER : itn[b]+N_USER);
}

// ---- init facc from fp32 embeddings (layer-0 term, full precision) ------
__global__ void k_gacc0(const float* __restrict__ ei, const float* __restrict__ ep,
                        const int* __restrict__ tlist, float* __restrict__ facc){
    int t = blockIdx.x*blockDim.x + threadIdx.x;
    if(t >= NTGT*64) return;
    int j = t>>6, d = t&63;
    int n = tlist[j];
    facc[(size_t)j*128 + d]      = ei[(size_t)n*64 + d];
    facc[(size_t)j*128 + 64 + d] = ep[(size_t)n*64 + d];
}

// ---- facc += combined fp16 rows at target nodes -------------------------
__global__ void k_gaccC(const __half2* __restrict__ hC, const int* __restrict__ tlist,
                        float2* __restrict__ faccv){
    int t = blockIdx.x*blockDim.x + threadIdx.x;
    if(t >= NTGT*64) return;
    int j = t>>6, l = t&63;
    int n = tlist[j];
    float2 v = __half22float2(hC[(size_t)n*64 + l]);
    float2 a = faccv[(size_t)j*64 + l];
    a.x += v.x; a.y += v.y;
    faccv[(size_t)j*64 + l] = a;
}

// ---- all four score arrays in one pass ----------------------------------
__global__ void k_score(const float2* __restrict__ faccv,
                        float* __restrict__ p_int, float* __restrict__ n_int,
                        float* __restrict__ p_pop, float* __restrict__ n_pop){
    int t = blockIdx.x*blockDim.x + threadIdx.x;
    int b = t >> 6, l = t & 63;
    if(b >= BSZ) return;
    // float2 slots 0..31 = int dims, 32..63 = pop dims
    float2 u = faccv[(size_t)b*64 + l];
    float2 p = faccv[(size_t)(BSZ   + b)*64 + l];
    float2 n = faccv[(size_t)(2*BSZ + b)*64 + l];
    float dp = u.x*p.x + u.y*p.y;
    float dn = u.x*n.x + u.y*n.y;
    for(int off=16; off; off>>=1){ dp += __shfl_down(dp,off,32); dn += __shfl_down(dn,off,32); }
    if(l==0) { p_int[b] = dp*(1.f/16.f); n_int[b] = dn*(1.f/16.f); }
    if(l==32){ p_pop[b] = dp*(1.f/16.f); n_pop[b] = dn*(1.f/16.f); }
}

// ---- mask layout detect: byte-bool vs int32 -----------------------------
__global__ void k_maskdetect(const unsigned char* __restrict__ m, unsigned* __restrict__ flag){
    __shared__ int any;
    if(threadIdx.x==0) any=0;
    __syncthreads();
    for(int i=threadIdx.x;i<BSZ;i+=blockDim.x){ if((i&3) && m[i]) any=1; }
    __syncthreads();
    if(threadIdx.x==0) *flag = (any!=0) ? 1u : 0u;
}

// ---- final fused loss ---------------------------------------------------
__global__ __launch_bounds__(256) void k_loss(const float* __restrict__ p_int, const float* __restrict__ n_int,
                      const float* __restrict__ p_pop, const float* __restrict__ n_pop,
                      const float* __restrict__ q, const float* __restrict__ bq,
                      const int* __restrict__ item_p, const int* __restrict__ item_n,
                      const void* __restrict__ mask, const unsigned* __restrict__ mflag,
                      float* __restrict__ out){
    __shared__ float sh[4][256];
    float a0=0,a1=0,a2=0,a3=0;
    bool bytes = (*mflag)!=0;
    const unsigned char* m8 = (const unsigned char*)mask;
    const int* m32 = (const int*)mask;
    for(int i=threadIdx.x;i<BSZ;i+=256){
        float pi=p_int[i], ni=n_int[i], pp=p_pop[i], npp=n_pop[i];
        float mf = bytes ? (m8[i]?1.f:0.f) : (m32[i]?1.f:0.f);
        float nmf = 1.f-mf;
        a0 += mf  * logsigf(pi-ni);
        a1 += mf  * logsigf(npp-pp);
        a2 += nmf * logsigf(pp-npp);
        int ip=item_p[i], in_=item_n[i];
        float popp = softplusf(q[ip]) + softplusf(bq[ip]);
        float popn = softplusf(q[in_]) + softplusf(bq[in_]);
        a3 += logsigf(tanhf(popp)*(pi+pp) - tanhf(popn)*(ni+npp));
    }
    sh[0][threadIdx.x]=a0; sh[1][threadIdx.x]=a1; sh[2][threadIdx.x]=a2; sh[3][threadIdx.x]=a3;
    __syncthreads();
    for(int off=128; off; off>>=1){
        if(threadIdx.x < off){
            sh[0][threadIdx.x]+=sh[0][threadIdx.x+off];
            sh[1][threadIdx.x]+=sh[1][threadIdx.x+off];
            sh[2][threadIdx.x]+=sh[2][threadIdx.x+off];
            sh[3][threadIdx.x]+=sh[3][threadIdx.x+off];
        }
        __syncthreads();
    }
    if(threadIdx.x==0){
        const float invB = 1.f/(float)BSZ;
        float loss_int  = -sh[0][0]*invB;
        float loss_pop  = -sh[1][0]*invB + sh[2][0]*invB;
        float loss_tide = -sh[3][0]*invB;
        out[0] = 0.1f*loss_int + 0.1f*loss_pop + 0.2f*loss_tide;
    }
}

extern "C" void kernel_launch(void* const* d_in, const int* in_sizes, int n_in,
                              void* d_out, int out_size, void* d_ws, size_t ws_size,
                              hipStream_t stream){
    const float* emb_int = (const float*)d_in[0];
    const float* emb_pop = (const float*)d_in[1];
    const float* q    = (const float*)d_in[2];
    const float* bq   = (const float*)d_in[3];
    const int* user   = (const int*)d_in[4];
    const int* item_p = (const int*)d_in[5];
    const int* item_n = (const int*)d_in[6];
    const void* mask  = d_in[7];
    const int* esrc   = (const int*)d_in[8];
    const int* edst   = (const int*)d_in[9];

    char* ws = (char*)d_ws;
    size_t o = 0;
    auto take = [&](size_t bytes)->char*{ char* p = ws + o; o = (o + bytes + 255) & ~(size_t)255; return p; };
    unsigned* degO   = (unsigned*)take((size_t)NNODE*4);
    unsigned* degI   = (unsigned*)take((size_t)NNODE*4);
    unsigned* cursor = (unsigned*)take((size_t)NNODE*4);
    size_t zeroBytes = o;
    unsigned* rs     = (unsigned*)take((size_t)NNODE*4);
    unsigned* bsums  = (unsigned*)take(1024*4);
    int2*     ec     = (int2*)take((size_t)NEDGE*8);
    __half2*  hA     = (__half2*)take((size_t)NNODE*64*4);   // 150K x 128 fp16
    __half2*  hB     = (__half2*)take((size_t)NNODE*64*4);
    float*    facc   = (float*)take((size_t)NTGT*128*4);
    int*      tlist  = (int*)take((size_t)NTGT*4);
    float*    sc     = (float*)take((size_t)4*BSZ*4);
    unsigned* mflag  = (unsigned*)take(256);
    (void)ws_size; (void)in_sizes; (void)n_in; (void)out_size;

    float* p_int = sc;          float* n_int = sc + BSZ;
    float* p_pop = sc + 2*BSZ;  float* n_pop = sc + 3*BSZ;
    float2* faccv = (float2*)facc;

    hipMemsetAsync(ws, 0, zeroBytes, stream);

    const int eb = (NEDGE + 255)/256;
    k_deg<<<eb,256,0,stream>>>(esrc, edst, degO, degI);
    const int sb = (NNODE + 1023)/1024;
    k_scan1<<<sb,1024,0,stream>>>(degI, rs, bsums);
    k_scan2<<<1,64,0,stream>>>(bsums, sb);
    k_scan3<<<sb,1024,0,stream>>>(rs, bsums);
    k_bucket<<<eb,256,0,stream>>>(esrc, edst, degO, degI, rs, cursor, ec);
    k_maskdetect<<<1,256,0,stream>>>((const unsigned char*)mask, mflag);
    k_tlist<<<(NTGT+255)/256,256,0,stream>>>(user, item_p, item_n, tlist);
    k_prep<<<(NNODE*32+255)/256,256,0,stream>>>((const float2*)emb_int, (const float2*)emb_pop, hA);
    k_gacc0<<<(NTGT*64+255)/256,256,0,stream>>>(emb_int, emb_pop, tlist, facc);

    const int spB = (NNODE*64 + 255)/256;
    const int gB  = (NTGT*64 + 255)/256;
    k_spmm_c<<<spB,256,0,stream>>>(hA, hB, rs, degI, ec);          // layer 1
    k_gaccC<<<gB,256,0,stream>>>(hB, tlist, faccv);
    k_spmm_c<<<spB,256,0,stream>>>(hB, hA, rs, degI, ec);          // layer 2
    k_gaccC<<<gB,256,0,stream>>>(hA, tlist, faccv);
    k_spmm_t<<<(NTGT*64+255)/256,256,0,stream>>>(hA, faccv, rs, degI, ec, tlist); // layer 3 @ targets

    k_score<<<(BSZ*64+255)/256,256,0,stream>>>(faccv, p_int, n_int, p_pop, n_pop);
    k_loss<<<1,256,0,stream>>>(p_int,n_int,p_pop,n_pop,q,bq,item_p,item_n,mask,mflag,(float*)d_out);
}

// Round 3
// 590.163 us; speedup vs baseline: 2.9205x; 1.2443x over previous
//
#include <hip/hip_runtime.h>
#include <hip/hip_bf16.h>
#include <hip/hip_fp16.h>
#include <math.h>

#define N_USER 100000
#define N_ITEM 50000
#define NNODE  150000   // N_USER + N_ITEM
#define DIM    64
#define NEDGE  2000000
#define BSZ    8192
#define NTGT   (3*BSZ)
#define CB     586      // ceil(NNODE/256) coarse buckets
#define NB     512      // edge chunks
#define CH     ((NEDGE + NB - 1)/NB)   // 3907 edges per chunk

__device__ __forceinline__ float logsigf(float x){
    return fminf(x, 0.f) - log1pf(expf(-fabsf(x)));
}
__device__ __forceinline__ float softplusf(float x){
    return fmaxf(x, 0.f) + log1pf(expf(-fabsf(x)));
}

// ==== CSR build: two-level counting sort, LDS atomics only ===============

// A1: per-chunk coarse histograms (dst and src), bin-major layout [bin][chunk]
__global__ __launch_bounds__(256) void k_hist(const int* __restrict__ src, const int* __restrict__ dst,
                       unsigned* __restrict__ histD, unsigned* __restrict__ histS){
    __shared__ unsigned hD[CB], hS[CB];
    for(int i=threadIdx.x;i<CB;i+=256){ hD[i]=0; hS[i]=0; }
    __syncthreads();
    int lo = blockIdx.x*CH, hi = min(lo+CH, NEDGE);
    for(int e=lo+threadIdx.x; e<hi; e+=256){
        atomicAdd(&hS[src[e]>>8],1u);
        atomicAdd(&hD[dst[e]>>8],1u);
    }
    __syncthreads();
    for(int i=threadIdx.x;i<CB;i+=256){
        histD[(size_t)i*NB + blockIdx.x]=hD[i];
        histS[(size_t)i*NB + blockIdx.x]=hS[i];
    }
}

// A2a: exclusive scan along chunks for each bucket (in place), emit bucket totals
__global__ __launch_bounds__(512) void k_colscan(unsigned* __restrict__ histD, unsigned* __restrict__ histS,
                          unsigned* __restrict__ ctD, unsigned* __restrict__ ctS){
    unsigned* hist = blockIdx.y ? histS : histD;
    unsigned* ct   = blockIdx.y ? ctS   : ctD;
    int b = blockIdx.x;
    __shared__ unsigned sh[512];
    unsigned v = hist[(size_t)b*NB + threadIdx.x];
    sh[threadIdx.x] = v;
    __syncthreads();
    for(int off=1; off<512; off<<=1){
        unsigned t = (threadIdx.x>=off)? sh[threadIdx.x-off] : 0u;
        __syncthreads();
        sh[threadIdx.x] += t;
        __syncthreads();
    }
    hist[(size_t)b*NB + threadIdx.x] = sh[threadIdx.x] - v;  // exclusive within bucket
    if(threadIdx.x==511) ct[b] = sh[511];
}

// A2b: exclusive scan of bucket totals -> bucket segment starts (both arrays)
__global__ __launch_bounds__(1024) void k_bstart(const unsigned* __restrict__ ctD, const unsigned* __restrict__ ctS,
                         unsigned* __restrict__ bsD, unsigned* __restrict__ bsS){
    __shared__ unsigned sh[1024];
    unsigned v = (threadIdx.x<CB)? ctD[threadIdx.x] : 0u;
    sh[threadIdx.x]=v; __syncthreads();
    for(int off=1; off<1024; off<<=1){ unsigned t=(threadIdx.x>=off)?sh[threadIdx.x-off]:0u; __syncthreads(); sh[threadIdx.x]+=t; __syncthreads(); }
    if(threadIdx.x<CB) bsD[threadIdx.x]=sh[threadIdx.x]-v;
    if(threadIdx.x==CB-1) bsD[CB]=sh[threadIdx.x];
    __syncthreads();
    unsigned v2 = (threadIdx.x<CB)? ctS[threadIdx.x] : 0u;
    sh[threadIdx.x]=v2; __syncthreads();
    for(int off=1; off<1024; off<<=1){ unsigned t=(threadIdx.x>=off)?sh[threadIdx.x-off]:0u; __syncthreads(); sh[threadIdx.x]+=t; __syncthreads(); }
    if(threadIdx.x<CB) bsS[threadIdx.x]=sh[threadIdx.x]-v2;
    if(threadIdx.x==CB-1) bsS[CB]=sh[threadIdx.x];
}

// A3: scatter edges into coarse buckets via LDS cursors (exact offsets, no global atomics)
__global__ __launch_bounds__(256) void k_scatter(const int* __restrict__ src, const int* __restrict__ dst,
                          const unsigned* __restrict__ histD, const unsigned* __restrict__ histS,
                          const unsigned* __restrict__ bsD, const unsigned* __restrict__ bsS,
                          int2* __restrict__ part, int* __restrict__ spart){
    __shared__ unsigned curD[CB], curS[CB];
    for(int i=threadIdx.x;i<CB;i+=256){
        curD[i]=bsD[i]+histD[(size_t)i*NB+blockIdx.x];
        curS[i]=bsS[i]+histS[(size_t)i*NB+blockIdx.x];
    }
    __syncthreads();
    int lo=blockIdx.x*CH, hi=min(lo+CH,NEDGE);
    for(int e=lo+threadIdx.x;e<hi;e+=256){
        int s=src[e], d=dst[e];
        unsigned pD=atomicAdd(&curD[d>>8],1u);
        part[pD]=make_int2(s,d);
        unsigned pS=atomicAdd(&curS[s>>8],1u);
        spart[pS]=s;
    }
}

// B-src: fine count per node -> rsqrt(max(deg_out,1)) directly
__global__ __launch_bounds__(256) void k_degO(const int* __restrict__ spart, const unsigned* __restrict__ bsS,
                       float* __restrict__ rsqO){
    __shared__ unsigned cnt[256];
    cnt[threadIdx.x]=0;
    __syncthreads();
    unsigned lo=bsS[blockIdx.x], hi=bsS[blockIdx.x+1];
    for(unsigned e=lo+threadIdx.x;e<hi;e+=256) atomicAdd(&cnt[spart[e]&255],1u);
    __syncthreads();
    int node=(blockIdx.x<<8)+(int)threadIdx.x;
    if(node<NNODE) rsqO[node]=rsqrtf(fmaxf((float)cnt[threadIdx.x],1.f));
}

// B-dst: fine count + block scan -> degI/rs; scatter to final CSR with weight folded in
__global__ __launch_bounds__(256) void k_csr(const int2* __restrict__ part, const unsigned* __restrict__ bsD,
                      const float* __restrict__ rsqO,
                      unsigned* __restrict__ rs, unsigned* __restrict__ degI,
                      int2* __restrict__ ec){
    __shared__ unsigned cnt[256], cur[256], sh[256];
    __shared__ float rsq[256];
    cnt[threadIdx.x]=0;
    __syncthreads();
    unsigned lo=bsD[blockIdx.x], hi=bsD[blockIdx.x+1];
    for(unsigned e=lo+threadIdx.x;e<hi;e+=256) atomicAdd(&cnt[part[e].y&255],1u);
    __syncthreads();
    unsigned c=cnt[threadIdx.x];
    sh[threadIdx.x]=c; __syncthreads();
    for(int o=1;o<256;o<<=1){ unsigned t=(threadIdx.x>=o)?sh[threadIdx.x-o]:0u; __syncthreads(); sh[threadIdx.x]+=t; __syncthreads(); }
    unsigned ex = sh[threadIdx.x]-c;
    rsq[threadIdx.x]=rsqrtf(fmaxf((float)c,1.f));
    cur[threadIdx.x]=lo+ex;
    int node=(blockIdx.x<<8)+(int)threadIdx.x;
    if(node<NNODE){ degI[node]=c; rs[node]=lo+ex; }
    __syncthreads();
    for(unsigned e=lo+threadIdx.x;e<hi;e+=256){
        int2 p=part[e];
        int fb=p.y&255;
        unsigned pos=atomicAdd(&cur[fb],1u);
        float w=rsq[fb]*rsqO[p.x];
        ec[pos]=make_int2(p.x,__float_as_int(w));
    }
}

// ==== propagation ========================================================

// interleave emb_int|emb_pop into fp16 combined rows [node][128]
__global__ void k_prep(const float2* __restrict__ ei, const float2* __restrict__ ep,
                       __half2* __restrict__ hC){
    int idx = blockIdx.x*blockDim.x + threadIdx.x;
    if(idx >= NNODE*32) return;
    int n = idx>>5, p = idx&31;
    hC[(size_t)n*64 + p]      = __float22half2_rn(ei[(size_t)n*32+p]);
    hC[(size_t)n*64 + 32 + p] = __float22half2_rn(ep[(size_t)n*32+p]);
}

// combined SpMM (both tables at once), one wave per dst row
__global__ __launch_bounds__(256) void k_spmm_c(const __half2* __restrict__ hin, __half2* __restrict__ hout,
                                                const unsigned* __restrict__ rs, const unsigned* __restrict__ degI,
                                                const int2* __restrict__ ec){
    int w = (blockIdx.x*blockDim.x + threadIdx.x) >> 6;
    int lane = threadIdx.x & 63;
    if(w >= NNODE) return;
    unsigned start = (unsigned)__builtin_amdgcn_readfirstlane((int)rs[w]);
    unsigned cnt   = (unsigned)__builtin_amdgcn_readfirstlane((int)degI[w]);
    float ax=0.f, ay=0.f;
    unsigned i=0;
    for(; i+2<=cnt; i+=2){
        int2 e0 = ec[start+i];
        int2 e1 = ec[start+i+1];
        float w0 = __int_as_float(e0.y), w1 = __int_as_float(e1.y);
        float2 v0 = __half22float2(hin[(size_t)e0.x*64 + lane]);
        float2 v1 = __half22float2(hin[(size_t)e1.x*64 + lane]);
        ax += w0*v0.x; ay += w0*v0.y;
        ax += w1*v1.x; ay += w1*v1.y;
    }
    if(i<cnt){
        int2 e0 = ec[start+i];
        float w0 = __int_as_float(e0.y);
        float2 v0 = __half22float2(hin[(size_t)e0.x*64 + lane]);
        ax += w0*v0.x; ay += w0*v0.y;
    }
    hout[(size_t)w*64 + lane] = __float22half2_rn(make_float2(ax,ay));
}

// layer-3 SpMM restricted to target rows, accumulate fp32
__global__ __launch_bounds__(256) void k_spmm_t(const __half2* __restrict__ hin, float2* __restrict__ faccv,
                                                const unsigned* __restrict__ rs, const unsigned* __restrict__ degI,
                                                const int2* __restrict__ ec, const int* __restrict__ tlist){
    int w = (blockIdx.x*blockDim.x + threadIdx.x) >> 6;
    int lane = threadIdx.x & 63;
    if(w >= NTGT) return;
    int node = __builtin_amdgcn_readfirstlane(tlist[w]);
    unsigned start = (unsigned)__builtin_amdgcn_readfirstlane((int)rs[node]);
    unsigned cnt   = (unsigned)__builtin_amdgcn_readfirstlane((int)degI[node]);
    float ax=0.f, ay=0.f;
    unsigned i=0;
    for(; i+2<=cnt; i+=2){
        int2 e0 = ec[start+i];
        int2 e1 = ec[start+i+1];
        float w0 = __int_as_float(e0.y), w1 = __int_as_float(e1.y);
        float2 v0 = __half22float2(hin[(size_t)e0.x*64 + lane]);
        float2 v1 = __half22float2(hin[(size_t)e1.x*64 + lane]);
        ax += w0*v0.x; ay += w0*v0.y;
        ax += w1*v1.x; ay += w1*v1.y;
    }
    if(i<cnt){
        int2 e0 = ec[start+i];
        float w0 = __int_as_float(e0.y);
        float2 v0 = __half22float2(hin[(size_t)e0.x*64 + lane]);
        ax += w0*v0.x; ay += w0*v0.y;
    }
    float2 a = faccv[(size_t)w*64 + lane];
    a.x += ax; a.y += ay;
    faccv[(size_t)w*64 + lane] = a;
}

// target node-id list
__global__ void k_tlist(const int* __restrict__ user, const int* __restrict__ itp,
                        const int* __restrict__ itn, int* __restrict__ tlist){
    int j = blockIdx.x*blockDim.x + threadIdx.x;
    if(j >= NTGT) return;
    int sec = j>>13, b = j&(BSZ-1);
    tlist[j] = (sec==0) ? user[b] : ((sec==1) ? itp[b]+N_USER : itn[b]+N_USER);
}

// init facc from fp32 embeddings (layer-0 term, full precision)
__global__ void k_gacc0(const float* __restrict__ ei, const float* __restrict__ ep,
                        const int* __restrict__ tlist, float* __restrict__ facc){
    int t = blockIdx.x*blockDim.x + threadIdx.x;
    if(t >= NTGT*64) return;
    int j = t>>6, d = t&63;
    int n = tlist[j];
    facc[(size_t)j*128 + d]      = ei[(size_t)n*64 + d];
    facc[(size_t)j*128 + 64 + d] = ep[(size_t)n*64 + d];
}

// facc += combined fp16 rows at target nodes
__global__ void k_gaccC(const __half2* __restrict__ hC, const int* __restrict__ tlist,
                        float2* __restrict__ faccv){
    int t = blockIdx.x*blockDim.x + threadIdx.x;
    if(t >= NTGT*64) return;
    int j = t>>6, l = t&63;
    int n = tlist[j];
    float2 v = __half22float2(hC[(size_t)n*64 + l]);
    float2 a = faccv[(size_t)j*64 + l];
    a.x += v.x; a.y += v.y;
    faccv[(size_t)j*64 + l] = a;
}

// all four score arrays in one pass
__global__ void k_score(const float2* __restrict__ faccv,
                        float* __restrict__ p_int, float* __restrict__ n_int,
                        float* __restrict__ p_pop, float* __restrict__ n_pop){
    int t = blockIdx.x*blockDim.x + threadIdx.x;
    int b = t >> 6, l = t & 63;
    if(b >= BSZ) return;
    float2 u = faccv[(size_t)b*64 + l];
    float2 p = faccv[(size_t)(BSZ   + b)*64 + l];
    float2 n = faccv[(size_t)(2*BSZ + b)*64 + l];
    float dp = u.x*p.x + u.y*p.y;
    float dn = u.x*n.x + u.y*n.y;
    for(int off=16; off; off>>=1){ dp += __shfl_down(dp,off,32); dn += __shfl_down(dn,off,32); }
    if(l==0) { p_int[b] = dp*(1.f/16.f); n_int[b] = dn*(1.f/16.f); }
    if(l==32){ p_pop[b] = dp*(1.f/16.f); n_pop[b] = dn*(1.f/16.f); }
}

// mask layout detect: byte-bool vs int32
__global__ void k_maskdetect(const unsigned char* __restrict__ m, unsigned* __restrict__ flag){
    __shared__ int any;
    if(threadIdx.x==0) any=0;
    __syncthreads();
    for(int i=threadIdx.x;i<BSZ;i+=blockDim.x){ if((i&3) && m[i]) any=1; }
    __syncthreads();
    if(threadIdx.x==0) *flag = (any!=0) ? 1u : 0u;
}

// final fused loss
__global__ __launch_bounds__(256) void k_loss(const float* __restrict__ p_int, const float* __restrict__ n_int,
                      const float* __restrict__ p_pop, const float* __restrict__ n_pop,
                      const float* __restrict__ q, const float* __restrict__ bq,
                      const int* __restrict__ item_p, const int* __restrict__ item_n,
                      const void* __restrict__ mask, const unsigned* __restrict__ mflag,
                      float* __restrict__ out){
    __shared__ float sh[4][256];
    float a0=0,a1=0,a2=0,a3=0;
    bool bytes = (*mflag)!=0;
    const unsigned char* m8 = (const unsigned char*)mask;
    const int* m32 = (const int*)mask;
    for(int i=threadIdx.x;i<BSZ;i+=256){
        float pi=p_int[i], ni=n_int[i], pp=p_pop[i], npp=n_pop[i];
        float mf = bytes ? (m8[i]?1.f:0.f) : (m32[i]?1.f:0.f);
        float nmf = 1.f-mf;
        a0 += mf  * logsigf(pi-ni);
        a1 += mf  * logsigf(npp-pp);
        a2 += nmf * logsigf(pp-npp);
        int ip=item_p[i], in_=item_n[i];
        float popp = softplusf(q[ip]) + softplusf(bq[ip]);
        float popn = softplusf(q[in_]) + softplusf(bq[in_]);
        a3 += logsigf(tanhf(popp)*(pi+pp) - tanhf(popn)*(ni+npp));
    }
    sh[0][threadIdx.x]=a0; sh[1][threadIdx.x]=a1; sh[2][threadIdx.x]=a2; sh[3][threadIdx.x]=a3;
    __syncthreads();
    for(int off=128; off; off>>=1){
        if(threadIdx.x < off){
            sh[0][threadIdx.x]+=sh[0][threadIdx.x+off];
            sh[1][threadIdx.x]+=sh[1][threadIdx.x+off];
            sh[2][threadIdx.x]+=sh[2][threadIdx.x+off];
            sh[3][threadIdx.x]+=sh[3][threadIdx.x+off];
        }
        __syncthreads();
    }
    if(threadIdx.x==0){
        const float invB = 1.f/(float)BSZ;
        float loss_int  = -sh[0][0]*invB;
        float loss_pop  = -sh[1][0]*invB + sh[2][0]*invB;
        float loss_tide = -sh[3][0]*invB;
        out[0] = 0.1f*loss_int + 0.1f*loss_pop + 0.2f*loss_tide;
    }
}

extern "C" void kernel_launch(void* const* d_in, const int* in_sizes, int n_in,
                              void* d_out, int out_size, void* d_ws, size_t ws_size,
                              hipStream_t stream){
    const float* emb_int = (const float*)d_in[0];
    const float* emb_pop = (const float*)d_in[1];
    const float* q    = (const float*)d_in[2];
    const float* bq   = (const float*)d_in[3];
    const int* user   = (const int*)d_in[4];
    const int* item_p = (const int*)d_in[5];
    const int* item_n = (const int*)d_in[6];
    const void* mask  = d_in[7];
    const int* esrc   = (const int*)d_in[8];
    const int* edst   = (const int*)d_in[9];

    char* ws = (char*)d_ws;
    size_t o = 0;
    auto take = [&](size_t bytes)->char*{ char* p = ws + o; o = (o + bytes + 255) & ~(size_t)255; return p; };
    unsigned* histD = (unsigned*)take((size_t)CB*NB*4);
    unsigned* histS = (unsigned*)take((size_t)CB*NB*4);
    unsigned* ctD   = (unsigned*)take((size_t)CB*4);
    unsigned* ctS   = (unsigned*)take((size_t)CB*4);
    unsigned* bsD   = (unsigned*)take((size_t)(CB+1)*4);
    unsigned* bsS   = (unsigned*)take((size_t)(CB+1)*4);
    int2*     part  = (int2*)take((size_t)NEDGE*8);
    int*      spart = (int*)take((size_t)NEDGE*4);
    float*    rsqO  = (float*)take((size_t)NNODE*4);
    unsigned* degI  = (unsigned*)take((size_t)NNODE*4);
    unsigned* rs    = (unsigned*)take((size_t)NNODE*4);
    int2*     ec    = (int2*)take((size_t)NEDGE*8);
    __half2*  hA    = (__half2*)take((size_t)NNODE*64*4);
    __half2*  hB    = (__half2*)take((size_t)NNODE*64*4);
    float*    facc  = (float*)take((size_t)NTGT*128*4);
    int*      tlist = (int*)take((size_t)NTGT*4);
    float*    sc    = (float*)take((size_t)4*BSZ*4);
    unsigned* mflag = (unsigned*)take(256);
    (void)ws_size; (void)in_sizes; (void)n_in; (void)out_size;

    float* p_int = sc;          float* n_int = sc + BSZ;
    float* p_pop = sc + 2*BSZ;  float* n_pop = sc + 3*BSZ;
    float2* faccv = (float2*)facc;

    // CSR build (no global atomics)
    k_hist<<<NB,256,0,stream>>>(esrc, edst, histD, histS);
    k_colscan<<<dim3(CB,2),512,0,stream>>>(histD, histS, ctD, ctS);
    k_bstart<<<1,1024,0,stream>>>(ctD, ctS, bsD, bsS);
    k_scatter<<<NB,256,0,stream>>>(esrc, edst, histD, histS, bsD, bsS, part, spart);
    k_degO<<<CB,256,0,stream>>>(spart, bsS, rsqO);
    k_csr<<<CB,256,0,stream>>>(part, bsD, rsqO, rs, degI, ec);

    k_maskdetect<<<1,256,0,stream>>>((const unsigned char*)mask, mflag);
    k_tlist<<<(NTGT+255)/256,256,0,stream>>>(user, item_p, item_n, tlist);
    k_prep<<<(NNODE*32+255)/256,256,0,stream>>>((const float2*)emb_int, (const float2*)emb_pop, hA);
    k_gacc0<<<(NTGT*64+255)/256,256,0,stream>>>(emb_int, emb_pop, tlist, facc);

    const int spB = (NNODE*64 + 255)/256;
    const int gB  = (NTGT*64 + 255)/256;
    k_spmm_c<<<spB,256,0,stream>>>(hA, hB, rs, degI, ec);          // layer 1
    k_gaccC<<<gB,256,0,stream>>>(hB, tlist, faccv);
    k_spmm_c<<<spB,256,0,stream>>>(hB, hA, rs, degI, ec);          // layer 2
    k_gaccC<<<gB,256,0,stream>>>(hA, tlist, faccv);
    k_spmm_t<<<(NTGT*64+255)/256,256,0,stream>>>(hA, faccv, rs, degI, ec, tlist); // layer 3 @ targets

    k_score<<<(BSZ*64+255)/256,256,0,stream>>>(faccv, p_int, n_int, p_pop, n_pop);
    k_loss<<<1,256,0,stream>>>(p_int,n_int,p_pop,n_pop,q,bq,item_p,item_n,mask,mflag,(float*)d_out);
}

// Round 4
// 475.589 us; speedup vs baseline: 3.6241x; 1.2409x over previous
//
#include <hip/hip_runtime.h>
#include <hip/hip_bf16.h>
#include <hip/hip_fp16.h>
#include <math.h>

#define N_USER 100000
#define N_ITEM 50000
#define NNODE  150000   // N_USER + N_ITEM
#define DIM    64
#define NEDGE  2000000
#define BSZ    8192
#define NTGT   (3*BSZ)
#define CB     586      // ceil(NNODE/256) coarse buckets
#define NB     512      // edge chunks
#define CH     ((NEDGE + NB - 1)/NB)   // 3907 edges per chunk
#define LBLK   2048     // loss partial blocks (BSZ waves / 4 waves-per-block)

__device__ __forceinline__ float logsigf(float x){
    return fminf(x, 0.f) - log1pf(expf(-fabsf(x)));
}
__device__ __forceinline__ float softplusf(float x){
    return fmaxf(x, 0.f) + log1pf(expf(-fabsf(x)));
}

// ==== CSR build: two-level counting sort, LDS atomics only ===============

__global__ __launch_bounds__(256) void k_hist(const int* __restrict__ src, const int* __restrict__ dst,
                       unsigned* __restrict__ histD, unsigned* __restrict__ histS){
    __shared__ unsigned hD[CB], hS[CB];
    for(int i=threadIdx.x;i<CB;i+=256){ hD[i]=0; hS[i]=0; }
    __syncthreads();
    int lo = blockIdx.x*CH, hi = min(lo+CH, NEDGE);
    for(int e=lo+threadIdx.x; e<hi; e+=256){
        atomicAdd(&hS[src[e]>>8],1u);
        atomicAdd(&hD[dst[e]>>8],1u);
    }
    __syncthreads();
    for(int i=threadIdx.x;i<CB;i+=256){
        histD[(size_t)i*NB + blockIdx.x]=hD[i];
        histS[(size_t)i*NB + blockIdx.x]=hS[i];
    }
}

__global__ __launch_bounds__(512) void k_colscan(unsigned* __restrict__ histD, unsigned* __restrict__ histS,
                          unsigned* __restrict__ ctD, unsigned* __restrict__ ctS){
    unsigned* hist = blockIdx.y ? histS : histD;
    unsigned* ct   = blockIdx.y ? ctS   : ctD;
    int b = blockIdx.x;
    __shared__ unsigned sh[512];
    unsigned v = hist[(size_t)b*NB + threadIdx.x];
    sh[threadIdx.x] = v;
    __syncthreads();
    for(int off=1; off<512; off<<=1){
        unsigned t = (threadIdx.x>=off)? sh[threadIdx.x-off] : 0u;
        __syncthreads();
        sh[threadIdx.x] += t;
        __syncthreads();
    }
    hist[(size_t)b*NB + threadIdx.x] = sh[threadIdx.x] - v;
    if(threadIdx.x==511) ct[b] = sh[511];
}

__global__ __launch_bounds__(1024) void k_bstart(const unsigned* __restrict__ ctD, const unsigned* __restrict__ ctS,
                         unsigned* __restrict__ bsD, unsigned* __restrict__ bsS){
    __shared__ unsigned sh[1024];
    unsigned v = (threadIdx.x<CB)? ctD[threadIdx.x] : 0u;
    sh[threadIdx.x]=v; __syncthreads();
    for(int off=1; off<1024; off<<=1){ unsigned t=(threadIdx.x>=off)?sh[threadIdx.x-off]:0u; __syncthreads(); sh[threadIdx.x]+=t; __syncthreads(); }
    if(threadIdx.x<CB) bsD[threadIdx.x]=sh[threadIdx.x]-v;
    if(threadIdx.x==CB-1) bsD[CB]=sh[threadIdx.x];
    __syncthreads();
    unsigned v2 = (threadIdx.x<CB)? ctS[threadIdx.x] : 0u;
    sh[threadIdx.x]=v2; __syncthreads();
    for(int off=1; off<1024; off<<=1){ unsigned t=(threadIdx.x>=off)?sh[threadIdx.x-off]:0u; __syncthreads(); sh[threadIdx.x]+=t; __syncthreads(); }
    if(threadIdx.x<CB) bsS[threadIdx.x]=sh[threadIdx.x]-v2;
    if(threadIdx.x==CB-1) bsS[CB]=sh[threadIdx.x];
}

__global__ __launch_bounds__(256) void k_scatter(const int* __restrict__ src, const int* __restrict__ dst,
                          const unsigned* __restrict__ histD, const unsigned* __restrict__ histS,
                          const unsigned* __restrict__ bsD, const unsigned* __restrict__ bsS,
                          int2* __restrict__ part, int* __restrict__ spart){
    __shared__ unsigned curD[CB], curS[CB];
    for(int i=threadIdx.x;i<CB;i+=256){
        curD[i]=bsD[i]+histD[(size_t)i*NB+blockIdx.x];
        curS[i]=bsS[i]+histS[(size_t)i*NB+blockIdx.x];
    }
    __syncthreads();
    int lo=blockIdx.x*CH, hi=min(lo+CH,NEDGE);
    for(int e=lo+threadIdx.x;e<hi;e+=256){
        int s=src[e], d=dst[e];
        unsigned pD=atomicAdd(&curD[d>>8],1u);
        part[pD]=make_int2(s,d);
        unsigned pS=atomicAdd(&curS[s>>8],1u);
        spart[pS]=s;
    }
}

__global__ __launch_bounds__(256) void k_degO(const int* __restrict__ spart, const unsigned* __restrict__ bsS,
                       float* __restrict__ rsqO){
    __shared__ unsigned cnt[256];
    cnt[threadIdx.x]=0;
    __syncthreads();
    unsigned lo=bsS[blockIdx.x], hi=bsS[blockIdx.x+1];
    for(unsigned e=lo+threadIdx.x;e<hi;e+=256) atomicAdd(&cnt[spart[e]&255],1u);
    __syncthreads();
    int node=(blockIdx.x<<8)+(int)threadIdx.x;
    if(node<NNODE) rsqO[node]=rsqrtf(fmaxf((float)cnt[threadIdx.x],1.f));
}

__global__ __launch_bounds__(256) void k_csr(const int2* __restrict__ part, const unsigned* __restrict__ bsD,
                      const float* __restrict__ rsqO,
                      unsigned* __restrict__ rs, unsigned* __restrict__ degI,
                      int2* __restrict__ ec){
    __shared__ unsigned cnt[256], cur[256], sh[256];
    __shared__ float rsq[256];
    cnt[threadIdx.x]=0;
    __syncthreads();
    unsigned lo=bsD[blockIdx.x], hi=bsD[blockIdx.x+1];
    for(unsigned e=lo+threadIdx.x;e<hi;e+=256) atomicAdd(&cnt[part[e].y&255],1u);
    __syncthreads();
    unsigned c=cnt[threadIdx.x];
    sh[threadIdx.x]=c; __syncthreads();
    for(int o=1;o<256;o<<=1){ unsigned t=(threadIdx.x>=o)?sh[threadIdx.x-o]:0u; __syncthreads(); sh[threadIdx.x]+=t; __syncthreads(); }
    unsigned ex = sh[threadIdx.x]-c;
    rsq[threadIdx.x]=rsqrtf(fmaxf((float)c,1.f));
    cur[threadIdx.x]=lo+ex;
    int node=(blockIdx.x<<8)+(int)threadIdx.x;
    if(node<NNODE){ degI[node]=c; rs[node]=lo+ex; }
    __syncthreads();
    for(unsigned e=lo+threadIdx.x;e<hi;e+=256){
        int2 p=part[e];
        int fb=p.y&255;
        unsigned pos=atomicAdd(&cur[fb],1u);
        float w=rsq[fb]*rsqO[p.x];
        ec[pos]=make_int2(p.x,__float_as_int(w));
    }
}

// ==== propagation ========================================================

__global__ void k_prep(const float2* __restrict__ ei, const float2* __restrict__ ep,
                       __half2* __restrict__ hC){
    int idx = blockIdx.x*blockDim.x + threadIdx.x;
    if(idx >= NNODE*32) return;
    int n = idx>>5, p = idx&31;
    hC[(size_t)n*64 + p]      = __float22half2_rn(ei[(size_t)n*32+p]);
    hC[(size_t)n*64 + 32 + p] = __float22half2_rn(ep[(size_t)n*32+p]);
}

__global__ __launch_bounds__(256) void k_spmm_c(const __half2* __restrict__ hin, __half2* __restrict__ hout,
                                                const unsigned* __restrict__ rs, const unsigned* __restrict__ degI,
                                                const int2* __restrict__ ec){
    int w = (blockIdx.x*blockDim.x + threadIdx.x) >> 6;
    int lane = threadIdx.x & 63;
    if(w >= NNODE) return;
    unsigned start = (unsigned)__builtin_amdgcn_readfirstlane((int)rs[w]);
    unsigned cnt   = (unsigned)__builtin_amdgcn_readfirstlane((int)degI[w]);
    float ax=0.f, ay=0.f;
    unsigned i=0;
    for(; i+4<=cnt; i+=4){
        int2 e0 = ec[start+i];
        int2 e1 = ec[start+i+1];
        int2 e2 = ec[start+i+2];
        int2 e3 = ec[start+i+3];
        float2 v0 = __half22float2(hin[(size_t)e0.x*64 + lane]);
        float2 v1 = __half22float2(hin[(size_t)e1.x*64 + lane]);
        float2 v2 = __half22float2(hin[(size_t)e2.x*64 + lane]);
        float2 v3 = __half22float2(hin[(size_t)e3.x*64 + lane]);
        float w0=__int_as_float(e0.y), w1=__int_as_float(e1.y);
        float w2=__int_as_float(e2.y), w3=__int_as_float(e3.y);
        ax += w0*v0.x + w1*v1.x + w2*v2.x + w3*v3.x;
        ay += w0*v0.y + w1*v1.y + w2*v2.y + w3*v3.y;
    }
    for(; i<cnt; ++i){
        int2 e0 = ec[start+i];
        float w0 = __int_as_float(e0.y);
        float2 v0 = __half22float2(hin[(size_t)e0.x*64 + lane]);
        ax += w0*v0.x; ay += w0*v0.y;
    }
    hout[(size_t)w*64 + lane] = __float22half2_rn(make_float2(ax,ay));
}

__global__ __launch_bounds__(256) void k_spmm_t(const __half2* __restrict__ hin, float2* __restrict__ faccv,
                                                const unsigned* __restrict__ rs, const unsigned* __restrict__ degI,
                                                const int2* __restrict__ ec, const int* __restrict__ tlist){
    int w = (blockIdx.x*blockDim.x + threadIdx.x) >> 6;
    int lane = threadIdx.x & 63;
    if(w >= NTGT) return;
    int node = __builtin_amdgcn_readfirstlane(tlist[w]);
    unsigned start = (unsigned)__builtin_amdgcn_readfirstlane((int)rs[node]);
    unsigned cnt   = (unsigned)__builtin_amdgcn_readfirstlane((int)degI[node]);
    float ax=0.f, ay=0.f;
    unsigned i=0;
    for(; i+4<=cnt; i+=4){
        int2 e0 = ec[start+i];
        int2 e1 = ec[start+i+1];
        int2 e2 = ec[start+i+2];
        int2 e3 = ec[start+i+3];
        float2 v0 = __half22float2(hin[(size_t)e0.x*64 + lane]);
        float2 v1 = __half22float2(hin[(size_t)e1.x*64 + lane]);
        float2 v2 = __half22float2(hin[(size_t)e2.x*64 + lane]);
        float2 v3 = __half22float2(hin[(size_t)e3.x*64 + lane]);
        float w0=__int_as_float(e0.y), w1=__int_as_float(e1.y);
        float w2=__int_as_float(e2.y), w3=__int_as_float(e3.y);
        ax += w0*v0.x + w1*v1.x + w2*v2.x + w3*v3.x;
        ay += w0*v0.y + w1*v1.y + w2*v2.y + w3*v3.y;
    }
    for(; i<cnt; ++i){
        int2 e0 = ec[start+i];
        float w0 = __int_as_float(e0.y);
        float2 v0 = __half22float2(hin[(size_t)e0.x*64 + lane]);
        ax += w0*v0.x; ay += w0*v0.y;
    }
    float2 a = faccv[(size_t)w*64 + lane];
    a.x += ax; a.y += ay;
    faccv[(size_t)w*64 + lane] = a;
}

__global__ void k_tlist(const int* __restrict__ user, const int* __restrict__ itp,
                        const int* __restrict__ itn, int* __restrict__ tlist){
    int j = blockIdx.x*blockDim.x + threadIdx.x;
    if(j >= NTGT) return;
    int sec = j>>13, b = j&(BSZ-1);
    tlist[j] = (sec==0) ? user[b] : ((sec==1) ? itp[b]+N_USER : itn[b]+N_USER);
}

__global__ void k_gacc0(const float* __restrict__ ei, const float* __restrict__ ep,
                        const int* __restrict__ tlist, float* __restrict__ facc){
    int t = blockIdx.x*blockDim.x + threadIdx.x;
    if(t >= NTGT*64) return;
    int j = t>>6, d = t&63;
    int n = tlist[j];
    facc[(size_t)j*128 + d]      = ei[(size_t)n*64 + d];
    facc[(size_t)j*128 + 64 + d] = ep[(size_t)n*64 + d];
}

__global__ void k_gaccC(const __half2* __restrict__ hC, const int* __restrict__ tlist,
                        float2* __restrict__ faccv){
    int t = blockIdx.x*blockDim.x + threadIdx.x;
    if(t >= NTGT*64) return;
    int j = t>>6, l = t&63;
    int n = tlist[j];
    float2 v = __half22float2(hC[(size_t)n*64 + l]);
    float2 a = faccv[(size_t)j*64 + l];
    a.x += v.x; a.y += v.y;
    faccv[(size_t)j*64 + l] = a;
}

// ==== fused score + loss: one wave per sample, per-block partial sums ====
__global__ __launch_bounds__(256) void k_scoreloss(const float2* __restrict__ faccv,
                        const float* __restrict__ q, const float* __restrict__ bq,
                        const int* __restrict__ item_p, const int* __restrict__ item_n,
                        const void* __restrict__ mask, const unsigned* __restrict__ mflag,
                        float4* __restrict__ partial){
    int t = blockIdx.x*256 + threadIdx.x;
    int b = t >> 6, l = t & 63;
    int wv = threadIdx.x >> 6;
    __shared__ float4 wsum[4];
    // dot products: float2 slots 0..31 = int dims, 32..63 = pop dims
    float2 u = faccv[(size_t)b*64 + l];
    float2 p = faccv[(size_t)(BSZ   + b)*64 + l];
    float2 n = faccv[(size_t)(2*BSZ + b)*64 + l];
    float dp = u.x*p.x + u.y*p.y;
    float dn = u.x*n.x + u.y*n.y;
    for(int off=16; off; off>>=1){ dp += __shfl_down(dp,off,32); dn += __shfl_down(dn,off,32); }
    float pi  = __shfl(dp, 0, 64) * (1.f/16.f);
    float ni  = __shfl(dn, 0, 64) * (1.f/16.f);
    float pp  = __shfl(dp, 32, 64) * (1.f/16.f);
    float npp = __shfl(dn, 32, 64) * (1.f/16.f);
    float a0=0,a1=0,a2=0,a3=0;
    if(l == 0){
        bool bytes = (*mflag)!=0;
        float mf = bytes ? (((const unsigned char*)mask)[b]?1.f:0.f)
                         : (((const int*)mask)[b]?1.f:0.f);
        float nmf = 1.f-mf;
        a0 = mf  * logsigf(pi-ni);
        a1 = mf  * logsigf(npp-pp);
        a2 = nmf * logsigf(pp-npp);
        int ip=item_p[b], in_=item_n[b];
        float popp = softplusf(q[ip]) + softplusf(bq[ip]);
        float popn = softplusf(q[in_]) + softplusf(bq[in_]);
        a3 = logsigf(tanhf(popp)*(pi+pp) - tanhf(popn)*(ni+npp));
        wsum[wv] = make_float4(a0,a1,a2,a3);
    }
    __syncthreads();
    if(threadIdx.x == 0){
        float4 s0=wsum[0], s1=wsum[1], s2=wsum[2], s3=wsum[3];
        partial[blockIdx.x] = make_float4(s0.x+s1.x+s2.x+s3.x, s0.y+s1.y+s2.y+s3.y,
                                          s0.z+s1.z+s2.z+s3.z, s0.w+s1.w+s2.w+s3.w);
    }
}

__global__ __launch_bounds__(256) void k_lossfin(const float4* __restrict__ partial, float* __restrict__ out){
    __shared__ float4 sh[256];
    float4 s = make_float4(0,0,0,0);
    for(int i=threadIdx.x; i<LBLK; i+=256){
        float4 v = partial[i];
        s.x+=v.x; s.y+=v.y; s.z+=v.z; s.w+=v.w;
    }
    sh[threadIdx.x]=s;
    __syncthreads();
    for(int off=128; off; off>>=1){
        if(threadIdx.x < off){
            float4 a=sh[threadIdx.x], b2=sh[threadIdx.x+off];
            sh[threadIdx.x]=make_float4(a.x+b2.x,a.y+b2.y,a.z+b2.z,a.w+b2.w);
        }
        __syncthreads();
    }
    if(threadIdx.x==0){
        const float invB = 1.f/(float)BSZ;
        float4 t = sh[0];
        float loss_int  = -t.x*invB;
        float loss_pop  = -t.y*invB + t.z*invB;
        float loss_tide = -t.w*invB;
        out[0] = 0.1f*loss_int + 0.1f*loss_pop + 0.2f*loss_tide;
    }
}

__global__ void k_maskdetect(const unsigned char* __restrict__ m, unsigned* __restrict__ flag){
    __shared__ int any;
    if(threadIdx.x==0) any=0;
    __syncthreads();
    for(int i=threadIdx.x;i<BSZ;i+=blockDim.x){ if((i&3) && m[i]) any=1; }
    __syncthreads();
    if(threadIdx.x==0) *flag = (any!=0) ? 1u : 0u;
}

extern "C" void kernel_launch(void* const* d_in, const int* in_sizes, int n_in,
                              void* d_out, int out_size, void* d_ws, size_t ws_size,
                              hipStream_t stream){
    const float* emb_int = (const float*)d_in[0];
    const float* emb_pop = (const float*)d_in[1];
    const float* q    = (const float*)d_in[2];
    const float* bq   = (const float*)d_in[3];
    const int* user   = (const int*)d_in[4];
    const int* item_p = (const int*)d_in[5];
    const int* item_n = (const int*)d_in[6];
    const void* mask  = d_in[7];
    const int* esrc   = (const int*)d_in[8];
    const int* edst   = (const int*)d_in[9];

    char* ws = (char*)d_ws;
    size_t o = 0;
    auto take = [&](size_t bytes)->char*{ char* p = ws + o; o = (o + bytes + 255) & ~(size_t)255; return p; };
    unsigned* histD = (unsigned*)take((size_t)CB*NB*4);
    unsigned* histS = (unsigned*)take((size_t)CB*NB*4);
    unsigned* ctD   = (unsigned*)take((size_t)CB*4);
    unsigned* ctS   = (unsigned*)take((size_t)CB*4);
    unsigned* bsD   = (unsigned*)take((size_t)(CB+1)*4);
    unsigned* bsS   = (unsigned*)take((size_t)(CB+1)*4);
    int2*     part  = (int2*)take((size_t)NEDGE*8);
    int*      spart = (int*)take((size_t)NEDGE*4);
    float*    rsqO  = (float*)take((size_t)NNODE*4);
    unsigned* degI  = (unsigned*)take((size_t)NNODE*4);
    unsigned* rs    = (unsigned*)take((size_t)NNODE*4);
    int2*     ec    = (int2*)take((size_t)NEDGE*8);
    __half2*  hA    = (__half2*)take((size_t)NNODE*64*4);
    __half2*  hB    = (__half2*)take((size_t)NNODE*64*4);
    float*    facc  = (float*)take((size_t)NTGT*128*4);
    int*      tlist = (int*)take((size_t)NTGT*4);
    float4*   partial = (float4*)take((size_t)LBLK*16);
    unsigned* mflag = (unsigned*)take(256);
    (void)ws_size; (void)in_sizes; (void)n_in; (void)out_size;

    float2* faccv = (float2*)facc;

    // CSR build (no global atomics)
    k_hist<<<NB,256,0,stream>>>(esrc, edst, histD, histS);
    k_colscan<<<dim3(CB,2),512,0,stream>>>(histD, histS, ctD, ctS);
    k_bstart<<<1,1024,0,stream>>>(ctD, ctS, bsD, bsS);
    k_scatter<<<NB,256,0,stream>>>(esrc, edst, histD, histS, bsD, bsS, part, spart);
    k_degO<<<CB,256,0,stream>>>(spart, bsS, rsqO);
    k_csr<<<CB,256,0,stream>>>(part, bsD, rsqO, rs, degI, ec);

    k_maskdetect<<<1,256,0,stream>>>((const unsigned char*)mask, mflag);
    k_tlist<<<(NTGT+255)/256,256,0,stream>>>(user, item_p, item_n, tlist);
    k_prep<<<(NNODE*32+255)/256,256,0,stream>>>((const float2*)emb_int, (const float2*)emb_pop, hA);
    k_gacc0<<<(NTGT*64+255)/256,256,0,stream>>>(emb_int, emb_pop, tlist, facc);

    const int spB = (NNODE*64 + 255)/256;
    const int gB  = (NTGT*64 + 255)/256;
    k_spmm_c<<<spB,256,0,stream>>>(hA, hB, rs, degI, ec);          // layer 1
    k_gaccC<<<gB,256,0,stream>>>(hB, tlist, faccv);
    k_spmm_c<<<spB,256,0,stream>>>(hB, hA, rs, degI, ec);          // layer 2
    k_gaccC<<<gB,256,0,stream>>>(hA, tlist, faccv);
    k_spmm_t<<<(NTGT*64+255)/256,256,0,stream>>>(hA, faccv, rs, degI, ec, tlist); // layer 3 @ targets

    k_scoreloss<<<LBLK,256,0,stream>>>(faccv, q, bq, item_p, item_n, mask, mflag, partial);
    k_lossfin<<<1,256,0,stream>>>(partial, (float*)d_out);
}

// Round 5
// 422.022 us; speedup vs baseline: 4.0841x; 1.1269x over previous
//
#include <hip/hip_runtime.h>
#include <hip/hip_bf16.h>
#include <math.h>

#define N_USER 100000
#define N_ITEM 50000
#define NNODE  150000   // N_USER + N_ITEM
#define DIM    64
#define NEDGE  2000000
#define BSZ    8192
#define NTGT   (3*BSZ)
#define CB     586      // ceil(NNODE/256) coarse buckets
#define NB     512      // edge chunks
#define CH     ((NEDGE + NB - 1)/NB)
#define LBLK   2048     // loss partial blocks

typedef float v2f __attribute__((ext_vector_type(2)));

__device__ __forceinline__ float logsigf(float x){
    return fminf(x, 0.f) - log1pf(expf(-fabsf(x)));
}
__device__ __forceinline__ float softplusf(float x){
    return fmaxf(x, 0.f) + log1pf(expf(-fabsf(x)));
}
__device__ __forceinline__ v2f fp8x2_to_f32(unsigned short u){
    return __builtin_amdgcn_cvt_pk_f32_fp8((int)u, false);
}
__device__ __forceinline__ unsigned short f32_to_fp8x2(float a, float b){
    return (unsigned short)__builtin_amdgcn_cvt_pk_fp8_f32(a, b, 0, false);
}

// ==== CSR build: two-level counting sort, LDS atomics only ===============

__global__ __launch_bounds__(256) void k_hist(const int* __restrict__ src, const int* __restrict__ dst,
                       unsigned* __restrict__ histD, unsigned* __restrict__ histS){
    __shared__ unsigned hD[CB], hS[CB];
    for(int i=threadIdx.x;i<CB;i+=256){ hD[i]=0; hS[i]=0; }
    __syncthreads();
    int lo = blockIdx.x*CH, hi = min(lo+CH, NEDGE);
    for(int e=lo+threadIdx.x; e<hi; e+=256){
        atomicAdd(&hS[src[e]>>8],1u);
        atomicAdd(&hD[dst[e]>>8],1u);
    }
    __syncthreads();
    for(int i=threadIdx.x;i<CB;i+=256){
        histD[(size_t)i*NB + blockIdx.x]=hD[i];
        histS[(size_t)i*NB + blockIdx.x]=hS[i];
    }
}

__global__ __launch_bounds__(512) void k_colscan(unsigned* __restrict__ histD, unsigned* __restrict__ histS,
                          unsigned* __restrict__ ctD, unsigned* __restrict__ ctS){
    unsigned* hist = blockIdx.y ? histS : histD;
    unsigned* ct   = blockIdx.y ? ctS   : ctD;
    int b = blockIdx.x;
    __shared__ unsigned sh[512];
    unsigned v = hist[(size_t)b*NB + threadIdx.x];
    sh[threadIdx.x] = v;
    __syncthreads();
    for(int off=1; off<512; off<<=1){
        unsigned t = (threadIdx.x>=off)? sh[threadIdx.x-off] : 0u;
        __syncthreads();
        sh[threadIdx.x] += t;
        __syncthreads();
    }
    hist[(size_t)b*NB + threadIdx.x] = sh[threadIdx.x] - v;
    if(threadIdx.x==511) ct[b] = sh[511];
}

__global__ __launch_bounds__(1024) void k_bstart(const unsigned* __restrict__ ctD, const unsigned* __restrict__ ctS,
                         unsigned* __restrict__ bsD, unsigned* __restrict__ bsS){
    __shared__ unsigned sh[1024];
    unsigned v = (threadIdx.x<CB)? ctD[threadIdx.x] : 0u;
    sh[threadIdx.x]=v; __syncthreads();
    for(int off=1; off<1024; off<<=1){ unsigned t=(threadIdx.x>=off)?sh[threadIdx.x-off]:0u; __syncthreads(); sh[threadIdx.x]+=t; __syncthreads(); }
    if(threadIdx.x<CB) bsD[threadIdx.x]=sh[threadIdx.x]-v;
    if(threadIdx.x==CB-1) bsD[CB]=sh[threadIdx.x];
    __syncthreads();
    unsigned v2 = (threadIdx.x<CB)? ctS[threadIdx.x] : 0u;
    sh[threadIdx.x]=v2; __syncthreads();
    for(int off=1; off<1024; off<<=1){ unsigned t=(threadIdx.x>=off)?sh[threadIdx.x-off]:0u; __syncthreads(); sh[threadIdx.x]+=t; __syncthreads(); }
    if(threadIdx.x<CB) bsS[threadIdx.x]=sh[threadIdx.x]-v2;
    if(threadIdx.x==CB-1) bsS[CB]=sh[threadIdx.x];
}

__global__ __launch_bounds__(256) void k_scatter(const int* __restrict__ src, const int* __restrict__ dst,
                          const unsigned* __restrict__ histD, const unsigned* __restrict__ histS,
                          const unsigned* __restrict__ bsD, const unsigned* __restrict__ bsS,
                          int2* __restrict__ part, int* __restrict__ spart){
    __shared__ unsigned curD[CB], curS[CB];
    for(int i=threadIdx.x;i<CB;i+=256){
        curD[i]=bsD[i]+histD[(size_t)i*NB+blockIdx.x];
        curS[i]=bsS[i]+histS[(size_t)i*NB+blockIdx.x];
    }
    __syncthreads();
    int lo=blockIdx.x*CH, hi=min(lo+CH,NEDGE);
    for(int e=lo+threadIdx.x;e<hi;e+=256){
        int s=src[e], d=dst[e];
        unsigned pD=atomicAdd(&curD[d>>8],1u);
        part[pD]=make_int2(s,d);
        unsigned pS=atomicAdd(&curS[s>>8],1u);
        spart[pS]=s;
    }
}

__global__ __launch_bounds__(256) void k_degO(const int* __restrict__ spart, const unsigned* __restrict__ bsS,
                       float* __restrict__ rsqO){
    __shared__ unsigned cnt[256];
    cnt[threadIdx.x]=0;
    __syncthreads();
    unsigned lo=bsS[blockIdx.x], hi=bsS[blockIdx.x+1];
    for(unsigned e=lo+threadIdx.x;e<hi;e+=256) atomicAdd(&cnt[spart[e]&255],1u);
    __syncthreads();
    int node=(blockIdx.x<<8)+(int)threadIdx.x;
    if(node<NNODE) rsqO[node]=rsqrtf(fmaxf((float)cnt[threadIdx.x],1.f));
}

// fine count + block scan -> degI/rs; scatter CSR; edge packed (w14<<18)|src
__global__ __launch_bounds__(256) void k_csr(const int2* __restrict__ part, const unsigned* __restrict__ bsD,
                      const float* __restrict__ rsqO,
                      unsigned* __restrict__ rs, unsigned* __restrict__ degI,
                      unsigned* __restrict__ ec){
    __shared__ unsigned cnt[256], cur[256], sh[256];
    __shared__ float rsq[256];
    cnt[threadIdx.x]=0;
    __syncthreads();
    unsigned lo=bsD[blockIdx.x], hi=bsD[blockIdx.x+1];
    for(unsigned e=lo+threadIdx.x;e<hi;e+=256) atomicAdd(&cnt[part[e].y&255],1u);
    __syncthreads();
    unsigned c=cnt[threadIdx.x];
    sh[threadIdx.x]=c; __syncthreads();
    for(int o=1;o<256;o<<=1){ unsigned t=(threadIdx.x>=o)?sh[threadIdx.x-o]:0u; __syncthreads(); sh[threadIdx.x]+=t; __syncthreads(); }
    unsigned ex = sh[threadIdx.x]-c;
    rsq[threadIdx.x]=rsqrtf(fmaxf((float)c,1.f));
    cur[threadIdx.x]=lo+ex;
    int node=(blockIdx.x<<8)+(int)threadIdx.x;
    if(node<NNODE){ degI[node]=c; rs[node]=lo+ex; }
    __syncthreads();
    for(unsigned e=lo+threadIdx.x;e<hi;e+=256){
        int2 p=part[e];
        int fb=p.y&255;
        unsigned pos=atomicAdd(&cur[fb],1u);
        float w=rsq[fb]*rsqO[p.x];
        unsigned w14=(unsigned)(w*16383.f + 0.5f);
        ec[pos]=(w14<<18)|(unsigned)p.x;
    }
}

// ==== propagation ========================================================

// fp8-encode interleaved rows [node][128] (int|pop); last block: mask detect
__global__ __launch_bounds__(256) void k_prep(const float2* __restrict__ ei, const float2* __restrict__ ep,
                       unsigned short* __restrict__ hC,
                       const unsigned char* __restrict__ mask8, unsigned* __restrict__ mflag){
    if(blockIdx.x == gridDim.x-1){
        __shared__ int any;
        if(threadIdx.x==0) any=0;
        __syncthreads();
        for(int i=threadIdx.x;i<BSZ;i+=256){ if((i&3) && mask8[i]) any=1; }
        __syncthreads();
        if(threadIdx.x==0) *mflag = (any!=0) ? 1u : 0u;
        return;
    }
    int idx = blockIdx.x*256 + threadIdx.x;       // one ushort (2 dims) per thread
    int n = idx>>6, c = idx&63;
    float2 v = (c<32) ? ei[(size_t)n*32 + c] : ep[(size_t)n*32 + (c-32)];
    hC[(size_t)n*64 + c] = f32_to_fp8x2(v.x, v.y);
}

// combined SpMM over all nodes, fp8 rows, one wave per dst row
__global__ __launch_bounds__(256) void k_spmm_c(const unsigned short* __restrict__ hin, unsigned short* __restrict__ hout,
                                                const unsigned* __restrict__ rs, const unsigned* __restrict__ degI,
                                                const unsigned* __restrict__ ec){
    int w = (blockIdx.x*blockDim.x + threadIdx.x) >> 6;
    int lane = threadIdx.x & 63;
    if(w >= NNODE) return;
    unsigned start = (unsigned)__builtin_amdgcn_readfirstlane((int)rs[w]);
    unsigned cnt   = (unsigned)__builtin_amdgcn_readfirstlane((int)degI[w]);
    float ax=0.f, ay=0.f;
    unsigned i=0;
    for(; i+4<=cnt; i+=4){
        unsigned e0 = __builtin_nontemporal_load(&ec[start+i]);
        unsigned e1 = __builtin_nontemporal_load(&ec[start+i+1]);
        unsigned e2 = __builtin_nontemporal_load(&ec[start+i+2]);
        unsigned e3 = __builtin_nontemporal_load(&ec[start+i+3]);
        unsigned short u0 = hin[(size_t)(e0&0x3FFFFu)*64 + lane];
        unsigned short u1 = hin[(size_t)(e1&0x3FFFFu)*64 + lane];
        unsigned short u2 = hin[(size_t)(e2&0x3FFFFu)*64 + lane];
        unsigned short u3 = hin[(size_t)(e3&0x3FFFFu)*64 + lane];
        float w0=(float)(e0>>18)*(1.f/16383.f), w1=(float)(e1>>18)*(1.f/16383.f);
        float w2=(float)(e2>>18)*(1.f/16383.f), w3=(float)(e3>>18)*(1.f/16383.f);
        v2f v0=fp8x2_to_f32(u0), v1=fp8x2_to_f32(u1), v2=fp8x2_to_f32(u2), v3=fp8x2_to_f32(u3);
        ax += w0*v0.x + w1*v1.x + w2*v2.x + w3*v3.x;
        ay += w0*v0.y + w1*v1.y + w2*v2.y + w3*v3.y;
    }
    for(; i<cnt; ++i){
        unsigned e0 = __builtin_nontemporal_load(&ec[start+i]);
        float w0 = (float)(e0>>18)*(1.f/16383.f);
        v2f v0 = fp8x2_to_f32(hin[(size_t)(e0&0x3FFFFu)*64 + lane]);
        ax += w0*v0.x; ay += w0*v0.y;
    }
    hout[(size_t)w*64 + lane] = f32_to_fp8x2(ax, ay);
}

// layer-3 SpMM at target slots only, fp32 output rows
__global__ __launch_bounds__(256) void k_spmm_t(const unsigned short* __restrict__ hin, float2* __restrict__ h3,
                                                const unsigned* __restrict__ rs, const unsigned* __restrict__ degI,
                                                const unsigned* __restrict__ ec,
                                                const int* __restrict__ user, const int* __restrict__ itp,
                                                const int* __restrict__ itn){
    int w = (blockIdx.x*blockDim.x + threadIdx.x) >> 6;
    int lane = threadIdx.x & 63;
    if(w >= NTGT) return;
    int sec = w>>13, b = w&(BSZ-1);
    int node = (sec==0) ? user[b] : ((sec==1) ? itp[b]+N_USER : itn[b]+N_USER);
    node = __builtin_amdgcn_readfirstlane(node);
    unsigned start = (unsigned)__builtin_amdgcn_readfirstlane((int)rs[node]);
    unsigned cnt   = (unsigned)__builtin_amdgcn_readfirstlane((int)degI[node]);
    float ax=0.f, ay=0.f;
    unsigned i=0;
    for(; i+4<=cnt; i+=4){
        unsigned e0 = __builtin_nontemporal_load(&ec[start+i]);
        unsigned e1 = __builtin_nontemporal_load(&ec[start+i+1]);
        unsigned e2 = __builtin_nontemporal_load(&ec[start+i+2]);
        unsigned e3 = __builtin_nontemporal_load(&ec[start+i+3]);
        unsigned short u0 = hin[(size_t)(e0&0x3FFFFu)*64 + lane];
        unsigned short u1 = hin[(size_t)(e1&0x3FFFFu)*64 + lane];
        unsigned short u2 = hin[(size_t)(e2&0x3FFFFu)*64 + lane];
        unsigned short u3 = hin[(size_t)(e3&0x3FFFFu)*64 + lane];
        float w0=(float)(e0>>18)*(1.f/16383.f), w1=(float)(e1>>18)*(1.f/16383.f);
        float w2=(float)(e2>>18)*(1.f/16383.f), w3=(float)(e3>>18)*(1.f/16383.f);
        v2f v0=fp8x2_to_f32(u0), v1=fp8x2_to_f32(u1), v2=fp8x2_to_f32(u2), v3=fp8x2_to_f32(u3);
        ax += w0*v0.x + w1*v1.x + w2*v2.x + w3*v3.x;
        ay += w0*v0.y + w1*v1.y + w2*v2.y + w3*v3.y;
    }
    for(; i<cnt; ++i){
        unsigned e0 = __builtin_nontemporal_load(&ec[start+i]);
        float w0 = (float)(e0>>18)*(1.f/16383.f);
        v2f v0 = fp8x2_to_f32(hin[(size_t)(e0&0x3FFFFu)*64 + lane]);
        ax += w0*v0.x; ay += w0*v0.y;
    }
    h3[(size_t)w*64 + lane] = make_float2(ax, ay);
}

// ==== fused gather + score + loss: one wave per sample ===================
__global__ __launch_bounds__(256) void k_scoreloss(const float2* __restrict__ ei, const float2* __restrict__ ep,
                        const unsigned short* __restrict__ h1C, const unsigned short* __restrict__ h2C,
                        const float2* __restrict__ h3,
                        const float* __restrict__ q, const float* __restrict__ bq,
                        const int* __restrict__ user, const int* __restrict__ item_p, const int* __restrict__ item_n,
                        const void* __restrict__ mask, const unsigned* __restrict__ mflag,
                        float4* __restrict__ partial){
    int t = blockIdx.x*256 + threadIdx.x;
    int b = t >> 6, l = t & 63;
    int wv = threadIdx.x >> 6;
    __shared__ float4 wsum[4];
    int nu = user[b];
    int np = item_p[b] + N_USER;
    int nn = item_n[b] + N_USER;

    float2 e0u, e0p, e0n;
    if(l < 32){
        e0u = ei[(size_t)nu*32 + l]; e0p = ei[(size_t)np*32 + l]; e0n = ei[(size_t)nn*32 + l];
    } else {
        e0u = ep[(size_t)nu*32 + (l-32)]; e0p = ep[(size_t)np*32 + (l-32)]; e0n = ep[(size_t)nn*32 + (l-32)];
    }
    v2f h1u = fp8x2_to_f32(h1C[(size_t)nu*64 + l]);
    v2f h1p = fp8x2_to_f32(h1C[(size_t)np*64 + l]);
    v2f h1n = fp8x2_to_f32(h1C[(size_t)nn*64 + l]);
    v2f h2u = fp8x2_to_f32(h2C[(size_t)nu*64 + l]);
    v2f h2p = fp8x2_to_f32(h2C[(size_t)np*64 + l]);
    v2f h2n = fp8x2_to_f32(h2C[(size_t)nn*64 + l]);
    float2 h3u = h3[(size_t)b*64 + l];
    float2 h3p = h3[(size_t)(BSZ   + b)*64 + l];
    float2 h3n = h3[(size_t)(2*BSZ + b)*64 + l];

    float fux = e0u.x + h1u.x + h2u.x + h3u.x, fuy = e0u.y + h1u.y + h2u.y + h3u.y;
    float fpx = e0p.x + h1p.x + h2p.x + h3p.x, fpy = e0p.y + h1p.y + h2p.y + h3p.y;
    float fnx = e0n.x + h1n.x + h2n.x + h3n.x, fny = e0n.y + h1n.y + h2n.y + h3n.y;

    float dp = fux*fpx + fuy*fpy;
    float dn = fux*fnx + fuy*fny;
    for(int off=16; off; off>>=1){ dp += __shfl_down(dp,off,32); dn += __shfl_down(dn,off,32); }
    float pi  = __shfl(dp, 0, 64) * (1.f/16.f);
    float ni  = __shfl(dn, 0, 64) * (1.f/16.f);
    float pp  = __shfl(dp, 32, 64) * (1.f/16.f);
    float npp = __shfl(dn, 32, 64) * (1.f/16.f);
    if(l == 0){
        bool bytes = (*mflag)!=0;
        float mf = bytes ? (((const unsigned char*)mask)[b]?1.f:0.f)
                         : (((const int*)mask)[b]?1.f:0.f);
        float nmf = 1.f-mf;
        float a0 = mf  * logsigf(pi-ni);
        float a1 = mf  * logsigf(npp-pp);
        float a2 = nmf * logsigf(pp-npp);
        int ip=item_p[b], in_=item_n[b];
        float popp = softplusf(q[ip]) + softplusf(bq[ip]);
        float popn = softplusf(q[in_]) + softplusf(bq[in_]);
        float a3 = logsigf(tanhf(popp)*(pi+pp) - tanhf(popn)*(ni+npp));
        wsum[wv] = make_float4(a0,a1,a2,a3);
    }
    __syncthreads();
    if(threadIdx.x == 0){
        float4 s0=wsum[0], s1=wsum[1], s2=wsum[2], s3=wsum[3];
        partial[blockIdx.x] = make_float4(s0.x+s1.x+s2.x+s3.x, s0.y+s1.y+s2.y+s3.y,
                                          s0.z+s1.z+s2.z+s3.z, s0.w+s1.w+s2.w+s3.w);
    }
}

__global__ __launch_bounds__(256) void k_lossfin(const float4* __restrict__ partial, float* __restrict__ out){
    __shared__ float4 sh[256];
    float4 s = make_float4(0,0,0,0);
    for(int i=threadIdx.x; i<LBLK; i+=256){
        float4 v = partial[i];
        s.x+=v.x; s.y+=v.y; s.z+=v.z; s.w+=v.w;
    }
    sh[threadIdx.x]=s;
    __syncthreads();
    for(int off=128; off; off>>=1){
        if(threadIdx.x < off){
            float4 a=sh[threadIdx.x], b2=sh[threadIdx.x+off];
            sh[threadIdx.x]=make_float4(a.x+b2.x,a.y+b2.y,a.z+b2.z,a.w+b2.w);
        }
        __syncthreads();
    }
    if(threadIdx.x==0){
        const float invB = 1.f/(float)BSZ;
        float4 t = sh[0];
        float loss_int  = -t.x*invB;
        float loss_pop  = -t.y*invB + t.z*invB;
        float loss_tide = -t.w*invB;
        out[0] = 0.1f*loss_int + 0.1f*loss_pop + 0.2f*loss_tide;
    }
}

extern "C" void kernel_launch(void* const* d_in, const int* in_sizes, int n_in,
                              void* d_out, int out_size, void* d_ws, size_t ws_size,
                              hipStream_t stream){
    const float* emb_int = (const float*)d_in[0];
    const float* emb_pop = (const float*)d_in[1];
    const float* q    = (const float*)d_in[2];
    const float* bq   = (const float*)d_in[3];
    const int* user   = (const int*)d_in[4];
    const int* item_p = (const int*)d_in[5];
    const int* item_n = (const int*)d_in[6];
    const void* mask  = d_in[7];
    const int* esrc   = (const int*)d_in[8];
    const int* edst   = (const int*)d_in[9];

    char* ws = (char*)d_ws;
    size_t o = 0;
    auto take = [&](size_t bytes)->char*{ char* p = ws + o; o = (o + bytes + 255) & ~(size_t)255; return p; };
    unsigned* histD = (unsigned*)take((size_t)CB*NB*4);
    unsigned* histS = (unsigned*)take((size_t)CB*NB*4);
    unsigned* ctD   = (unsigned*)take((size_t)CB*4);
    unsigned* ctS   = (unsigned*)take((size_t)CB*4);
    unsigned* bsD   = (unsigned*)take((size_t)(CB+1)*4);
    unsigned* bsS   = (unsigned*)take((size_t)(CB+1)*4);
    int2*     part  = (int2*)take((size_t)NEDGE*8);
    int*      spart = (int*)take((size_t)NEDGE*4);
    float*    rsqO  = (float*)take((size_t)NNODE*4);
    unsigned* degI  = (unsigned*)take((size_t)NNODE*4);
    unsigned* rs    = (unsigned*)take((size_t)NNODE*4);
    unsigned* ec    = (unsigned*)take((size_t)NEDGE*4);
    unsigned short* hE  = (unsigned short*)take((size_t)NNODE*64*2);
    unsigned short* h1C = (unsigned short*)take((size_t)NNODE*64*2);
    unsigned short* h2C = (unsigned short*)take((size_t)NNODE*64*2);
    float2*   h3    = (float2*)take((size_t)NTGT*64*8);
    float4*   partial = (float4*)take((size_t)LBLK*16);
    unsigned* mflag = (unsigned*)take(256);
    (void)ws_size; (void)in_sizes; (void)n_in; (void)out_size;

    // CSR build (no global atomics)
    k_hist<<<NB,256,0,stream>>>(esrc, edst, histD, histS);
    k_colscan<<<dim3(CB,2),512,0,stream>>>(histD, histS, ctD, ctS);
    k_bstart<<<1,1024,0,stream>>>(ctD, ctS, bsD, bsS);
    k_scatter<<<NB,256,0,stream>>>(esrc, edst, histD, histS, bsD, bsS, part, spart);
    k_degO<<<CB,256,0,stream>>>(spart, bsS, rsqO);
    k_csr<<<CB,256,0,stream>>>(part, bsD, rsqO, rs, degI, ec);

    // fp8 encode of e0 (+ mask detect in last block)
    k_prep<<<NNODE*64/256 + 1,256,0,stream>>>((const float2*)emb_int, (const float2*)emb_pop,
                                              hE, (const unsigned char*)mask, mflag);

    const int spB = (NNODE*64 + 255)/256;
    k_spmm_c<<<spB,256,0,stream>>>(hE,  h1C, rs, degI, ec);        // layer 1
    k_spmm_c<<<spB,256,0,stream>>>(h1C, h2C, rs, degI, ec);        // layer 2
    k_spmm_t<<<(NTGT*64+255)/256,256,0,stream>>>(h2C, h3, rs, degI, ec, user, item_p, item_n); // layer 3

    k_scoreloss<<<LBLK,256,0,stream>>>((const float2*)emb_int, (const float2*)emb_pop,
                                       h1C, h2C, h3, q, bq, user, item_p, item_n,
                                       mask, mflag, partial);
    k_lossfin<<<1,256,0,stream>>>(partial, (float*)d_out);
}